// Round 9
// baseline (15263.269 us; speedup 1.0000x reference)
//
#include <hip/hip_runtime.h>
#include <stdint.h>

// GRU  B=128, T=1024, IN=256, H=512, OUT=1  (all fp32)
//
// v9 = v7/v8 with the coalesced write-back expressed via 32-bit stores only
// (LLVM rejects 128-bit inline-asm data operands, input OR tied; 32/64-bit
// operands are proven). Wave 0's 64 lanes store d = lane + 64k (k=0..3):
// each store instruction covers 4 rows x 16 consecutive dwords = 4 full 64B
// sectors -> same sectoring as dwordx4, 4 instrs/KB.
// v6-proven everything else:
//   256 wgs x 512 thr persistent kernel; 8 groups x 32 wgs; group = 16
//   samples; wg = 16 hidden j. Weights register-resident, asm-pinned.
//   h staged per step into chunk-padded LDS (16f chunks -> 20f). DPP rowsum.
//   Gates -> hnew_sh[16][20] (LDS), wave 0 writes back + sets flag; waves 1-7
//   run ahead into x-phase(t+1) (poll orders them). RMW-free monotonic flag
//   barrier via sc0/sc1 ops, s_sleep backoff, 1<<21 guard. Head = sep kernel.

#define B_    128
#define T_    1024
#define IN_   256
#define H_    512
#define NG    8
#define WPG   32
#define SGRP  16
#define JT    16
#define NT    512
#define RW    640                 // 32 chunks x 20 floats (padded)
#define LDS_DYN (SGRP*RW*4)       // 40,960 B h tile (+ static hnew_sh)

__device__ __forceinline__ float sig_(float v){ return 1.0f/(1.0f + __expf(-v)); }
__device__ __forceinline__ float tanh_(float v){
  float e = __expf(2.0f*v);       // tanh = 1 - 2/(e^{2x}+1); inf-safe
  return 1.0f - 2.0f/(e + 1.0f);
}

// IF-coherent (cache-bypassing) ops -- no L2 fences needed anywhere.
// NOTE: inline-asm DATA operands must be <=64-bit (128-bit rejected by LLVM).
#define CLOAD4(dst, p)  asm volatile("global_load_dwordx4 %0, %1, off sc0 sc1" : "=v"(dst) : "v"(p) : "memory")
#define CLOAD1(dst, p)  asm volatile("global_load_dword %0, %1, off sc0 sc1"   : "=v"(dst) : "v"(p) : "memory")
#define CSTORE1(p, v)   asm volatile("global_store_dword %0, %1, off sc0 sc1"  :: "v"(p), "v"(v) : "memory")
#define VWAIT0()        do{ asm volatile("s_waitcnt vmcnt(0)" ::: "memory"); __builtin_amdgcn_sched_barrier(0); }while(0)

#define FMA4A(acc, v, warr, base) do{           \
  acc = fmaf((v).x, warr[(base)+0], acc);       \
  acc = fmaf((v).y, warr[(base)+1], acc);       \
  acc = fmaf((v).z, warr[(base)+2], acc);       \
  acc = fmaf((v).w, warr[(base)+3], acc); }while(0)

// sum over each 16-lane row; full sum lands in lane 15 of the row (VALU DPP).
__device__ __forceinline__ float rowsum16(float v){
  float s = v; int t_;
  t_ = __builtin_amdgcn_update_dpp(0, __float_as_int(s), 0x111, 0xF, 0xF, true); s += __int_as_float(t_);
  t_ = __builtin_amdgcn_update_dpp(0, __float_as_int(s), 0x112, 0xF, 0xF, true); s += __int_as_float(t_);
  t_ = __builtin_amdgcn_update_dpp(0, __float_as_int(s), 0x114, 0xF, 0xF, true); s += __int_as_float(t_);
  t_ = __builtin_amdgcn_update_dpp(0, __float_as_int(s), 0x118, 0xF, 0xF, true); s += __int_as_float(t_);
  return s;
}

// poll all 32 group flags >= target. s_sleep backoff => low fabric pressure;
// guard 1<<21 (~0.3s) => spurious trips impossible.
__device__ __forceinline__ int poll_group(const int* fbase, int lane, int target){
  const int* fp = fbase + (lane & 31);
  int guard = 0;
  for (;;){
    int fv;
    CLOAD1(fv, fp);
    asm volatile("s_waitcnt vmcnt(0)" ::: "memory");
    if (__all(fv >= target)) return 0;
    __builtin_amdgcn_s_sleep(4);
    if (++guard > (1<<21)) return 1;
  }
}

// stage 16x512 h tile into chunk-padded LDS (thread = (ss, chunk))
__device__ __forceinline__ void stage_h(const float* hc, float* HT, int tid, int b0){
  const int ss = tid >> 5, c = tid & 31;
  const float* src = hc + (size_t)(b0+ss)*H_ + c*16;
  float4 v0,v1,v2,v3;
  CLOAD4(v0, src); CLOAD4(v1, (src+4)); CLOAD4(v2, (src+8)); CLOAD4(v3, (src+12));
  VWAIT0();
  float* d = HT + ss*RW + c*20;
  *(float4*)(d)    = v0; *(float4*)(d+4)  = v1;
  *(float4*)(d+8)  = v2; *(float4*)(d+12) = v3;
}

__global__ void __launch_bounds__(NT, 2)
rnn_persist(const float* __restrict__ x, const float* __restrict__ W_ih,
            const float* __restrict__ W_hh, const float* __restrict__ bias,
            const float* __restrict__ bias_n, float* __restrict__ h_buf,
            int* __restrict__ flags)
{
  extern __shared__ float HT[];        // [16][RW]
  __shared__ float hnew_sh[SGRP][20];  // wg's new h slice: [sample][j] (padded)

  const int bid = (int)blockIdx.x;
  const int g   = bid & (NG-1);
  const int w   = bid >> 3;
  const int tid = (int)threadIdx.x;
  const int j   = tid >> 5;            // [0,16)
  const int sg  = (tid >> 4) & 1;      // sample half
  const int ks  = tid & 15;            // k-group [0,16)
  const int jg  = w*JT + j;
  const int b0  = g*SGRP;
  const int lane = tid & 63;

  // ---- weights into registers (k-chunks ks and ks+16 for W_hh) ----
  float wr[32], wz[32], wn[32];
#pragma unroll
  for (int q=0;q<4;q++){
    *(float4*)&wr[4*q]    = *(const float4*)&W_hh[((size_t)0*H_ + jg)*H_ + ks*16 + 4*q];
    *(float4*)&wr[16+4*q] = *(const float4*)&W_hh[((size_t)0*H_ + jg)*H_ + (ks+16)*16 + 4*q];
    *(float4*)&wz[4*q]    = *(const float4*)&W_hh[((size_t)1*H_ + jg)*H_ + ks*16 + 4*q];
    *(float4*)&wz[16+4*q] = *(const float4*)&W_hh[((size_t)1*H_ + jg)*H_ + (ks+16)*16 + 4*q];
    *(float4*)&wn[4*q]    = *(const float4*)&W_hh[((size_t)2*H_ + jg)*H_ + ks*16 + 4*q];
    *(float4*)&wn[16+4*q] = *(const float4*)&W_hh[((size_t)2*H_ + jg)*H_ + (ks+16)*16 + 4*q];
  }
  float wxr[16], wxz[16], wxn[16];
#pragma unroll
  for (int q=0;q<4;q++){
    *(float4*)&wxr[4*q] = *(const float4*)&W_ih[((size_t)0*H_ + jg)*IN_ + ks*16 + 4*q];
    *(float4*)&wxz[4*q] = *(const float4*)&W_ih[((size_t)1*H_ + jg)*IN_ + ks*16 + 4*q];
    *(float4*)&wxn[4*q] = *(const float4*)&W_ih[((size_t)2*H_ + jg)*IN_ + ks*16 + 4*q];
  }
  float br = bias[jg], bz = bias[H_+jg], bni = bias[2*H_+jg], bnh = bias_n[jg];
  // pin: loads cannot be sunk back into the loop (round-2 failure mode)
#pragma unroll
  for (int i=0;i<32;i++) asm volatile("" : "+v"(wr[i]), "+v"(wz[i]), "+v"(wn[i]));
#pragma unroll
  for (int i=0;i<16;i++) asm volatile("" : "+v"(wxr[i]), "+v"(wxz[i]), "+v"(wxn[i]));
  asm volatile("" : "+v"(br), "+v"(bz), "+v"(bni), "+v"(bnh));

  float* const hb0 = h_buf;
  float* const hb1 = h_buf + (size_t)B_*H_;
  int dead = 0;

  for (int t=0; t<T_; ++t){
    const float* hc  = (t & 1) ? hb1 : hb0;
    float*       hnx = (t & 1) ? hb0 : hb1;

    // ---- x-phase (flag-independent; hides producer lag + HBM latency) ----
    float acc[8][4];   // [m][R,Z,NI,NH]
#pragma unroll
    for (int m=0;m<8;m++){
      const int ss = sg*8 + m;
      const float* xr = x + ((size_t)(b0+ss)*T_ + (size_t)t)*IN_ + ks*16;
      const float4 x0 = *(const float4*)(xr);
      const float4 x1 = *(const float4*)(xr+4);
      const float4 x2 = *(const float4*)(xr+8);
      const float4 x3 = *(const float4*)(xr+12);
      float aR=0.f, aZ=0.f, aNI=0.f;
      FMA4A(aR, x0, wxr, 0); FMA4A(aR, x1, wxr, 4); FMA4A(aR, x2, wxr, 8); FMA4A(aR, x3, wxr, 12);
      FMA4A(aZ, x0, wxz, 0); FMA4A(aZ, x1, wxz, 4); FMA4A(aZ, x2, wxz, 8); FMA4A(aZ, x3, wxz, 12);
      FMA4A(aNI,x0, wxn, 0); FMA4A(aNI,x1, wxn, 4); FMA4A(aNI,x2, wxn, 8); FMA4A(aNI,x3, wxn, 12);
      acc[m][0]=aR; acc[m][1]=aZ; acc[m][2]=aNI; acc[m][3]=0.f;
    }

    // ---- wait for h^t, then stage it into LDS ----
    if (t > 0 && !dead) dead = poll_group(flags + g*WPG, lane, t);
    stage_h(hc, HT, tid, b0);
    __syncthreads();                   // B: HT(t) complete

    // ---- h-phase: per sample, read padded LDS chunks, FMA vs reg weights ----
#pragma unroll
    for (int m=0;m<8;m++){
      const int ss = sg*8 + m;
      const float* hrow = HT + ss*RW;
      float aR = acc[m][0], aZ = acc[m][1], aNH = acc[m][3];
      {
        const float* p = hrow + ks*20;
        const float4 a0 = *(const float4*)(p);
        const float4 a1 = *(const float4*)(p+4);
        const float4 a2 = *(const float4*)(p+8);
        const float4 a3 = *(const float4*)(p+12);
        FMA4A(aR, a0, wr, 0);  FMA4A(aR, a1, wr, 4);  FMA4A(aR, a2, wr, 8);  FMA4A(aR, a3, wr, 12);
        FMA4A(aZ, a0, wz, 0);  FMA4A(aZ, a1, wz, 4);  FMA4A(aZ, a2, wz, 8);  FMA4A(aZ, a3, wz, 12);
        FMA4A(aNH,a0, wn, 0);  FMA4A(aNH,a1, wn, 4);  FMA4A(aNH,a2, wn, 8);  FMA4A(aNH,a3, wn, 12);
      }
      {
        const float* p = hrow + (ks+16)*20;
        const float4 a0 = *(const float4*)(p);
        const float4 a1 = *(const float4*)(p+4);
        const float4 a2 = *(const float4*)(p+8);
        const float4 a3 = *(const float4*)(p+12);
        FMA4A(aR, a0, wr, 16); FMA4A(aR, a1, wr, 20); FMA4A(aR, a2, wr, 24); FMA4A(aR, a3, wr, 28);
        FMA4A(aZ, a0, wz, 16); FMA4A(aZ, a1, wz, 20); FMA4A(aZ, a2, wz, 24); FMA4A(aZ, a3, wz, 28);
        FMA4A(aNH,a0, wn, 16); FMA4A(aNH,a1, wn, 20); FMA4A(aNH,a2, wn, 24); FMA4A(aNH,a3, wn, 28);
      }
      acc[m][0]=aR; acc[m][1]=aZ; acc[m][3]=aNH;
    }

    // ---- reduce over 16 ks-lanes (DPP, VALU pipe; sum lands at ks==15) ----
#pragma unroll
    for (int m=0;m<8;m++){
      acc[m][0] = rowsum16(acc[m][0]);
      acc[m][1] = rowsum16(acc[m][1]);
      acc[m][2] = rowsum16(acc[m][2]);
      acc[m][3] = rowsum16(acc[m][3]);
    }

    // ---- gates: lane ks==15 of each row owns (j, 8 samples) -> LDS ----
    if (ks == 15){
#pragma unroll
      for (int m=0;m<8;m++){
        const int ss = sg*8 + m;
        const float h_old = HT[ss*RW + w*20 + j];   // chunk w = h idx [16w,16w+16)
        const float r = sig_(acc[m][0] + br);
        const float z = sig_(acc[m][1] + bz);
        const float n = tanh_(acc[m][2] + bni + r*(acc[m][3] + bnh));
        hnew_sh[ss][j] = (1.0f - z)*n + z*h_old;
      }
    }
    __syncthreads();                   // A: hnew_sh complete; HT reads complete

    // ---- wave 0: coalesced write-back of the wg's 16x16 slice ----
    // lane stores dwords d = lane + 64k (k=0..3): per instruction the wave
    // covers 4 rows x 16 consecutive dwords = 4 full 64B sectors.
    if (tid < 64){
#pragma unroll
      for (int k=0;k<4;k++){
        const int d   = tid + 64*k;
        const int ss2 = d >> 4;        // sample [0,16)
        const int col = d & 15;        // j within slice
        const float hv = hnew_sh[ss2][col];
        CSTORE1(hnx + (size_t)(b0+ss2)*H_ + w*JT + col, hv);
      }
      asm volatile("s_waitcnt vmcnt(0)" ::: "memory");   // drain before flag
    }
    if (tid == 0){
      int* fp = &flags[g*WPG + w];
      const int fv = t + 1;
      CSTORE1(fp, fv);
    }
    // waves 1-7 run ahead into x-phase(t+1); the poll orders them.
  }
}

__global__ void head_k(const float* __restrict__ h, const float* __restrict__ W_out,
                       const float* __restrict__ b_out, float* __restrict__ out)
{
  const int b = (int)blockIdx.x;       // 128 blocks, one sample each
  const int l = (int)threadIdx.x;      // 64 lanes
  const float* hp = h + (size_t)b*H_ + l*8;
  const float* wp = W_out + l*8;
  float a = 0.f;
#pragma unroll
  for (int q=0;q<2;q++){
    const float4 hv = *(const float4*)(hp + 4*q);
    const float4 wv = *(const float4*)(wp + 4*q);
    a = fmaf(hv.x, wv.x, a); a = fmaf(hv.y, wv.y, a);
    a = fmaf(hv.z, wv.z, a); a = fmaf(hv.w, wv.w, a);
  }
#pragma unroll
  for (int m=1;m<64;m<<=1) a += __shfl_xor(a, m, 64);
  if (l == 0) out[b] = sig_(a + b_out[0]);
}

extern "C" void kernel_launch(void* const* d_in, const int* in_sizes, int n_in,
                              void* d_out, int out_size, void* d_ws, size_t ws_size,
                              hipStream_t stream)
{
  const float* x    = (const float*)d_in[0];
  const float* Wih  = (const float*)d_in[1];
  const float* Whh  = (const float*)d_in[2];
  const float* bias = (const float*)d_in[3];
  const float* bn   = (const float*)d_in[4];
  const float* Wout = (const float*)d_in[5];
  const float* bout = (const float*)d_in[6];
  float* out   = (float*)d_out;
  float* h_buf = (float*)d_ws;                                         // 512 KB
  int* flags   = (int*)((char*)d_ws + (size_t)2*B_*H_*sizeof(float));  // 1 KB used

  // zero h0 + flags every launch (captured into the graph)
  (void)hipMemsetAsync(d_ws, 0, (size_t)2*B_*H_*sizeof(float) + 4096, stream);

  (void)hipFuncSetAttribute((const void*)rnn_persist,
                            hipFuncAttributeMaxDynamicSharedMemorySize, LDS_DYN);

  void* args[7];
  args[0]=(void*)&x;    args[1]=(void*)&Wih;  args[2]=(void*)&Whh; args[3]=(void*)&bias;
  args[4]=(void*)&bn;   args[5]=(void*)&h_buf; args[6]=(void*)&flags;
  hipError_t e = hipLaunchCooperativeKernel((const void*)rnn_persist,
                                            dim3(256), dim3(NT), args, LDS_DYN, stream);
  if (e != hipSuccess){
    (void)hipGetLastError();
    rnn_persist<<<dim3(256), dim3(NT), LDS_DYN, stream>>>(x, Wih, Whh, bias, bn, h_buf, flags);
  }
  // T_ even -> final h in hb0; kernel boundary makes h_buf coherent for head_k
  head_k<<<dim3(128), dim3(64), 0, stream>>>(h_buf, Wout, bout, out);
}

// Round 10
// 12547.329 us; speedup vs baseline: 1.2165x; 1.2165x over previous
//
#include <hip/hip_runtime.h>
#include <stdint.h>

// GRU  B=128, T=1024, IN=256, H=512, OUT=1  (all fp32)
//
// v10 = v9 (passed 2x, 15.3ms) + two fixes aimed at the REAL bottleneck:
//  (1) amdgpu_waves_per_eu(2,2): v9's VGPR_Count=128 proves the allocator
//      targeted 4 waves/EU and spilled the 148 pinned weight floats to
//      scratch (the ~2GB excess WRITE_SIZE). Pinning the occupancy range to
//      exactly 2 waves/EU gives a 256-VGPR budget -> weights truly resident.
//  (2) wave0-only fabric poll (+1 barrier): v9 had all 2048 waves gather the
//      same two 64B flag sectors every ~100ns -> fabric hot-spot on the
//      recurrent critical path. Now 256 polling waves.
// Everything else identical to v9:
//   256 wgs x 512 thr persistent kernel; 8 groups x 32 wgs; group = 16
//   samples; wg = 16 hidden j. Weights register-resident, asm-pinned.
//   h staged per step into chunk-padded LDS (16f chunks -> 20f). DPP rowsum.
//   Gates -> hnew_sh (LDS); wave0 coalesced write-back (4 full 64B sectors
//   per store instr) + monotonic flag. RMW-free sc0/sc1 flag barrier,
//   s_sleep backoff, 1<<21 guard. Head = separate kernel.

#define B_    128
#define T_    1024
#define IN_   256
#define H_    512
#define NG    8
#define WPG   32
#define SGRP  16
#define JT    16
#define NT    512
#define RW    640                 // 32 chunks x 20 floats (padded)
#define LDS_DYN (SGRP*RW*4)       // 40,960 B h tile (+ static hnew_sh)

__device__ __forceinline__ float sig_(float v){ return 1.0f/(1.0f + __expf(-v)); }
__device__ __forceinline__ float tanh_(float v){
  float e = __expf(2.0f*v);       // tanh = 1 - 2/(e^{2x}+1); inf-safe
  return 1.0f - 2.0f/(e + 1.0f);
}

// IF-coherent (cache-bypassing) ops -- no L2 fences needed anywhere.
// NOTE: inline-asm DATA operands must be <=64-bit (128-bit rejected by LLVM).
#define CLOAD4(dst, p)  asm volatile("global_load_dwordx4 %0, %1, off sc0 sc1" : "=v"(dst) : "v"(p) : "memory")
#define CLOAD1(dst, p)  asm volatile("global_load_dword %0, %1, off sc0 sc1"   : "=v"(dst) : "v"(p) : "memory")
#define CSTORE1(p, v)   asm volatile("global_store_dword %0, %1, off sc0 sc1"  :: "v"(p), "v"(v) : "memory")
#define VWAIT0()        do{ asm volatile("s_waitcnt vmcnt(0)" ::: "memory"); __builtin_amdgcn_sched_barrier(0); }while(0)

#define FMA4A(acc, v, warr, base) do{           \
  acc = fmaf((v).x, warr[(base)+0], acc);       \
  acc = fmaf((v).y, warr[(base)+1], acc);       \
  acc = fmaf((v).z, warr[(base)+2], acc);       \
  acc = fmaf((v).w, warr[(base)+3], acc); }while(0)

// sum over each 16-lane row; full sum lands in lane 15 of the row (VALU DPP).
__device__ __forceinline__ float rowsum16(float v){
  float s = v; int t_;
  t_ = __builtin_amdgcn_update_dpp(0, __float_as_int(s), 0x111, 0xF, 0xF, true); s += __int_as_float(t_);
  t_ = __builtin_amdgcn_update_dpp(0, __float_as_int(s), 0x112, 0xF, 0xF, true); s += __int_as_float(t_);
  t_ = __builtin_amdgcn_update_dpp(0, __float_as_int(s), 0x114, 0xF, 0xF, true); s += __int_as_float(t_);
  t_ = __builtin_amdgcn_update_dpp(0, __float_as_int(s), 0x118, 0xF, 0xF, true); s += __int_as_float(t_);
  return s;
}

// poll all 32 group flags >= target (wave0 only in v10). s_sleep backoff;
// guard 1<<21 (~0.3s) => spurious trips impossible.
__device__ __forceinline__ int poll_group(const int* fbase, int lane, int target){
  const int* fp = fbase + (lane & 31);
  int guard = 0;
  for (;;){
    int fv;
    CLOAD1(fv, fp);
    asm volatile("s_waitcnt vmcnt(0)" ::: "memory");
    if (__all(fv >= target)) return 0;
    __builtin_amdgcn_s_sleep(4);
    if (++guard > (1<<21)) return 1;
  }
}

// stage 16x512 h tile into chunk-padded LDS (thread = (ss, chunk))
__device__ __forceinline__ void stage_h(const float* hc, float* HT, int tid, int b0){
  const int ss = tid >> 5, c = tid & 31;
  const float* src = hc + (size_t)(b0+ss)*H_ + c*16;
  float4 v0,v1,v2,v3;
  CLOAD4(v0, src); CLOAD4(v1, (src+4)); CLOAD4(v2, (src+8)); CLOAD4(v3, (src+12));
  VWAIT0();
  float* d = HT + ss*RW + c*20;
  *(float4*)(d)    = v0; *(float4*)(d+4)  = v1;
  *(float4*)(d+8)  = v2; *(float4*)(d+12) = v3;
}

__global__ void __launch_bounds__(NT)
__attribute__((amdgpu_waves_per_eu(2, 2)))
rnn_persist(const float* __restrict__ x, const float* __restrict__ W_ih,
            const float* __restrict__ W_hh, const float* __restrict__ bias,
            const float* __restrict__ bias_n, float* __restrict__ h_buf,
            int* __restrict__ flags)
{
  extern __shared__ float HT[];        // [16][RW]
  __shared__ float hnew_sh[SGRP][20];  // wg's new h slice: [sample][j] (padded)

  const int bid = (int)blockIdx.x;
  const int g   = bid & (NG-1);
  const int w   = bid >> 3;
  const int tid = (int)threadIdx.x;
  const int j   = tid >> 5;            // [0,16)
  const int sg  = (tid >> 4) & 1;      // sample half
  const int ks  = tid & 15;            // k-group [0,16)
  const int jg  = w*JT + j;
  const int b0  = g*SGRP;
  const int lane = tid & 63;

  // ---- weights into registers (k-chunks ks and ks+16 for W_hh) ----
  float wr[32], wz[32], wn[32];
#pragma unroll
  for (int q=0;q<4;q++){
    *(float4*)&wr[4*q]    = *(const float4*)&W_hh[((size_t)0*H_ + jg)*H_ + ks*16 + 4*q];
    *(float4*)&wr[16+4*q] = *(const float4*)&W_hh[((size_t)0*H_ + jg)*H_ + (ks+16)*16 + 4*q];
    *(float4*)&wz[4*q]    = *(const float4*)&W_hh[((size_t)1*H_ + jg)*H_ + ks*16 + 4*q];
    *(float4*)&wz[16+4*q] = *(const float4*)&W_hh[((size_t)1*H_ + jg)*H_ + (ks+16)*16 + 4*q];
    *(float4*)&wn[4*q]    = *(const float4*)&W_hh[((size_t)2*H_ + jg)*H_ + ks*16 + 4*q];
    *(float4*)&wn[16+4*q] = *(const float4*)&W_hh[((size_t)2*H_ + jg)*H_ + (ks+16)*16 + 4*q];
  }
  float wxr[16], wxz[16], wxn[16];
#pragma unroll
  for (int q=0;q<4;q++){
    *(float4*)&wxr[4*q] = *(const float4*)&W_ih[((size_t)0*H_ + jg)*IN_ + ks*16 + 4*q];
    *(float4*)&wxz[4*q] = *(const float4*)&W_ih[((size_t)1*H_ + jg)*IN_ + ks*16 + 4*q];
    *(float4*)&wxn[4*q] = *(const float4*)&W_ih[((size_t)2*H_ + jg)*IN_ + ks*16 + 4*q];
  }
  float br = bias[jg], bz = bias[H_+jg], bni = bias[2*H_+jg], bnh = bias_n[jg];
  // pin: loads cannot be sunk back into the loop (round-2 failure mode)
#pragma unroll
  for (int i=0;i<32;i++) asm volatile("" : "+v"(wr[i]), "+v"(wz[i]), "+v"(wn[i]));
#pragma unroll
  for (int i=0;i<16;i++) asm volatile("" : "+v"(wxr[i]), "+v"(wxz[i]), "+v"(wxn[i]));
  asm volatile("" : "+v"(br), "+v"(bz), "+v"(bni), "+v"(bnh));

  float* const hb0 = h_buf;
  float* const hb1 = h_buf + (size_t)B_*H_;
  int dead = 0;

  for (int t=0; t<T_; ++t){
    const float* hc  = (t & 1) ? hb1 : hb0;
    float*       hnx = (t & 1) ? hb0 : hb1;

    // ---- x-phase (flag-independent; hides producer lag + HBM latency) ----
    float acc[8][4];   // [m][R,Z,NI,NH]
#pragma unroll
    for (int m=0;m<8;m++){
      const int ss = sg*8 + m;
      const float* xr = x + ((size_t)(b0+ss)*T_ + (size_t)t)*IN_ + ks*16;
      const float4 x0 = *(const float4*)(xr);
      const float4 x1 = *(const float4*)(xr+4);
      const float4 x2 = *(const float4*)(xr+8);
      const float4 x3 = *(const float4*)(xr+12);
      float aR=0.f, aZ=0.f, aNI=0.f;
      FMA4A(aR, x0, wxr, 0); FMA4A(aR, x1, wxr, 4); FMA4A(aR, x2, wxr, 8); FMA4A(aR, x3, wxr, 12);
      FMA4A(aZ, x0, wxz, 0); FMA4A(aZ, x1, wxz, 4); FMA4A(aZ, x2, wxz, 8); FMA4A(aZ, x3, wxz, 12);
      FMA4A(aNI,x0, wxn, 0); FMA4A(aNI,x1, wxn, 4); FMA4A(aNI,x2, wxn, 8); FMA4A(aNI,x3, wxn, 12);
      acc[m][0]=aR; acc[m][1]=aZ; acc[m][2]=aNI; acc[m][3]=0.f;
    }

    // ---- wave0 polls for h^t; other waves wait at barrier P ----
    if (tid < 64 && t > 0 && !dead) dead = poll_group(flags + g*WPG, lane, t);
    __syncthreads();                   // P: h^t globally visible
    stage_h(hc, HT, tid, b0);
    __syncthreads();                   // B: HT(t) complete

    // ---- h-phase: per sample, read padded LDS chunks, FMA vs reg weights ----
#pragma unroll
    for (int m=0;m<8;m++){
      const int ss = sg*8 + m;
      const float* hrow = HT + ss*RW;
      float aR = acc[m][0], aZ = acc[m][1], aNH = acc[m][3];
      {
        const float* p = hrow + ks*20;
        const float4 a0 = *(const float4*)(p);
        const float4 a1 = *(const float4*)(p+4);
        const float4 a2 = *(const float4*)(p+8);
        const float4 a3 = *(const float4*)(p+12);
        FMA4A(aR, a0, wr, 0);  FMA4A(aR, a1, wr, 4);  FMA4A(aR, a2, wr, 8);  FMA4A(aR, a3, wr, 12);
        FMA4A(aZ, a0, wz, 0);  FMA4A(aZ, a1, wz, 4);  FMA4A(aZ, a2, wz, 8);  FMA4A(aZ, a3, wz, 12);
        FMA4A(aNH,a0, wn, 0);  FMA4A(aNH,a1, wn, 4);  FMA4A(aNH,a2, wn, 8);  FMA4A(aNH,a3, wn, 12);
      }
      {
        const float* p = hrow + (ks+16)*20;
        const float4 a0 = *(const float4*)(p);
        const float4 a1 = *(const float4*)(p+4);
        const float4 a2 = *(const float4*)(p+8);
        const float4 a3 = *(const float4*)(p+12);
        FMA4A(aR, a0, wr, 16); FMA4A(aR, a1, wr, 20); FMA4A(aR, a2, wr, 24); FMA4A(aR, a3, wr, 28);
        FMA4A(aZ, a0, wz, 16); FMA4A(aZ, a1, wz, 20); FMA4A(aZ, a2, wz, 24); FMA4A(aZ, a3, wz, 28);
        FMA4A(aNH,a0, wn, 16); FMA4A(aNH,a1, wn, 20); FMA4A(aNH,a2, wn, 24); FMA4A(aNH,a3, wn, 28);
      }
      acc[m][0]=aR; acc[m][1]=aZ; acc[m][3]=aNH;
    }

    // ---- reduce over 16 ks-lanes (DPP, VALU pipe; sum lands at ks==15) ----
#pragma unroll
    for (int m=0;m<8;m++){
      acc[m][0] = rowsum16(acc[m][0]);
      acc[m][1] = rowsum16(acc[m][1]);
      acc[m][2] = rowsum16(acc[m][2]);
      acc[m][3] = rowsum16(acc[m][3]);
    }

    // ---- gates: lane ks==15 of each row owns (j, 8 samples) -> LDS ----
    if (ks == 15){
#pragma unroll
      for (int m=0;m<8;m++){
        const int ss = sg*8 + m;
        const float h_old = HT[ss*RW + w*20 + j];   // chunk w = h idx [16w,16w+16)
        const float r = sig_(acc[m][0] + br);
        const float z = sig_(acc[m][1] + bz);
        const float n = tanh_(acc[m][2] + bni + r*(acc[m][3] + bnh));
        hnew_sh[ss][j] = (1.0f - z)*n + z*h_old;
      }
    }
    __syncthreads();                   // A: hnew_sh complete; HT reads complete

    // ---- wave 0: coalesced write-back of the wg's 16x16 slice ----
    // lane stores dwords d = lane + 64k (k=0..3): per instruction the wave
    // covers 4 rows x 16 consecutive dwords = 4 full 64B sectors.
    if (tid < 64){
#pragma unroll
      for (int k=0;k<4;k++){
        const int d   = tid + 64*k;
        const int ss2 = d >> 4;        // sample [0,16)
        const int col = d & 15;        // j within slice
        const float hv = hnew_sh[ss2][col];
        CSTORE1(hnx + (size_t)(b0+ss2)*H_ + w*JT + col, hv);
      }
      asm volatile("s_waitcnt vmcnt(0)" ::: "memory");   // drain before flag
    }
    if (tid == 0){
      int* fp = &flags[g*WPG + w];
      const int fv = t + 1;
      CSTORE1(fp, fv);
    }
    // waves 1-7 run ahead into x-phase(t+1); barrier P orders them.
  }
}

__global__ void head_k(const float* __restrict__ h, const float* __restrict__ W_out,
                       const float* __restrict__ b_out, float* __restrict__ out)
{
  const int b = (int)blockIdx.x;       // 128 blocks, one sample each
  const int l = (int)threadIdx.x;      // 64 lanes
  const float* hp = h + (size_t)b*H_ + l*8;
  const float* wp = W_out + l*8;
  float a = 0.f;
#pragma unroll
  for (int q=0;q<2;q++){
    const float4 hv = *(const float4*)(hp + 4*q);
    const float4 wv = *(const float4*)(wp + 4*q);
    a = fmaf(hv.x, wv.x, a); a = fmaf(hv.y, wv.y, a);
    a = fmaf(hv.z, wv.z, a); a = fmaf(hv.w, wv.w, a);
  }
#pragma unroll
  for (int m=1;m<64;m<<=1) a += __shfl_xor(a, m, 64);
  if (l == 0) out[b] = sig_(a + b_out[0]);
}

extern "C" void kernel_launch(void* const* d_in, const int* in_sizes, int n_in,
                              void* d_out, int out_size, void* d_ws, size_t ws_size,
                              hipStream_t stream)
{
  const float* x    = (const float*)d_in[0];
  const float* Wih  = (const float*)d_in[1];
  const float* Whh  = (const float*)d_in[2];
  const float* bias = (const float*)d_in[3];
  const float* bn   = (const float*)d_in[4];
  const float* Wout = (const float*)d_in[5];
  const float* bout = (const float*)d_in[6];
  float* out   = (float*)d_out;
  float* h_buf = (float*)d_ws;                                         // 512 KB
  int* flags   = (int*)((char*)d_ws + (size_t)2*B_*H_*sizeof(float));  // 1 KB used

  // zero h0 + flags every launch (captured into the graph)
  (void)hipMemsetAsync(d_ws, 0, (size_t)2*B_*H_*sizeof(float) + 4096, stream);

  (void)hipFuncSetAttribute((const void*)rnn_persist,
                            hipFuncAttributeMaxDynamicSharedMemorySize, LDS_DYN);

  void* args[7];
  args[0]=(void*)&x;    args[1]=(void*)&Wih;  args[2]=(void*)&Whh; args[3]=(void*)&bias;
  args[4]=(void*)&bn;   args[5]=(void*)&h_buf; args[6]=(void*)&flags;
  hipError_t e = hipLaunchCooperativeKernel((const void*)rnn_persist,
                                            dim3(256), dim3(NT), args, LDS_DYN, stream);
  if (e != hipSuccess){
    (void)hipGetLastError();
    rnn_persist<<<dim3(256), dim3(NT), LDS_DYN, stream>>>(x, Wih, Whh, bias, bn, h_buf, flags);
  }
  // T_ even -> final h in hb0; kernel boundary makes h_buf coherent for head_k
  head_k<<<dim3(128), dim3(64), 0, stream>>>(h_buf, Wout, bout, out);
}